// Round 21
// baseline (125.617 us; speedup 1.0000x reference)
//
#include <hip/hip_runtime.h>
#include <hip/hip_bf16.h>

#define NN 8192
#define DD 128

typedef short short8 __attribute__((ext_vector_type(8)));
typedef __bf16 bf16x8 __attribute__((ext_vector_type(8)));
typedef float f32x4 __attribute__((ext_vector_type(4)));
typedef float f32x2 __attribute__((ext_vector_type(2)));

// unit-norm simplification (x2=y2=1):
//   d = 1 + c^2 - 2cs ;  q = nd^2 = 2c(1-s)/d ;  1-q = (1-c)^2/d exactly
//   rr = (1+nd)/(1-nd) = (1+nd)^2 * d/(1-c)^2
//   adc = -dist/T = KL*log2(rr) ; e = exp(adc) = exp2(KE*log2(rr))
// Symmetric: each unordered pair {i,j}, j<i computed once, credited to row i
// (registers) and col j (per-wave LDS). Complementary-strip pairing: strip I
// (128 rows) + strip 63-I = 520 cts constant. R21: 64 slots/unit of 8-9 cts
// (8x9+56x8=520) -> 2048 blocks = 8 blocks/CU = 8 waves/SIMD (final residency
// test; R19's 4 waves/SIMD sat at VALUBusy 43%).
#define MKc (-0.110803324099723f)   // -2c/(1-c)^2
#define PKc (0.110803324099723f)    // +2c/(1-c)^2
#define C1Kc (1.110803324099723f)   // (1+c^2)/(1-c)^2
#define KEc (-8.944271909999159f)   // -1/(sqrt_c*T)
#define KLc (-6.199696797323639f)   // KE*ln2

// ---------------- prep: normalize 16 rows/block -> bf16; zero accumulators ----------------
__global__ __launch_bounds__(256) void prep_kernel(const float* __restrict__ x,
                                                   __hip_bfloat16* __restrict__ fb,
                                                   float* __restrict__ totg,
                                                   float* __restrict__ tposg) {
  int r = threadIdx.x >> 4, sub = threadIdx.x & 15;
  int row = blockIdx.x * 16 + r;
  const float4 a = *(const float4*)(x + (size_t)row * DD + sub * 8);
  const float4 b = *(const float4*)(x + (size_t)row * DD + sub * 8 + 4);
  float ss = a.x * a.x + a.y * a.y + a.z * a.z + a.w * a.w +
             b.x * b.x + b.y * b.y + b.z * b.z + b.w * b.w;
  for (int off = 1; off < 16; off <<= 1) ss += __shfl_xor(ss, off, 16);
  float inv = 1.0f / fmaxf(sqrtf(ss), 1e-12f);
  float va[8] = {a.x, a.y, a.z, a.w, b.x, b.y, b.z, b.w};
  short8 h;
  for (int j = 0; j < 8; j++) {
    __hip_bfloat16 t = __float2bfloat16(va[j] * inv);
    h[j] = __builtin_bit_cast(short, t);
  }
  *(short8*)((short*)fb + (size_t)row * DD + sub * 8) = h;
  if (threadIdx.x < 16) {
    totg[blockIdx.x * 16 + threadIdx.x] = 0.f;
    tposg[blockIdx.x * 16 + threadIdx.x] = 0.f;
  }
}

// ---------------- fused symmetric, pair-balanced: 2048 blocks x 8-9 cts ----------------
// launch_bounds(256,2): natural VGPR, no spill (NEVER (256,4): 64-VGPR cap ->
// ~1GB scratch spill, R8/R9). No last-block finalize (R17: fences + 1-CU tail
// doubled fused time). Inner math identical to R16/R19 (validated, absmax 0.0).
__global__ __launch_bounds__(256, 2) void fused_kernel(
    const __hip_bfloat16* __restrict__ fbg,
    const int* __restrict__ plab, const int* __restrict__ slab,
    float* __restrict__ totg, float* __restrict__ tposg) {
  __shared__ float colT_l[4 * 144];    // per-wave col e-sums   (2304 B)
  __shared__ float colG_l[4 * 144];    // per-wave col lg-sums  (2304 B)

  const int tid = threadIdx.x;
  const int w = tid >> 6;
  const int lane = tid & 63;
  const int lrow = lane & 15;
  const int quad = lane >> 4;

  // block -> (unit u, slot k) -> ct window [s, s+c) over the unit's 520 cts
  const int u = blockIdx.x >> 6;
  const int k = blockIdx.x & 63;
  const int s = (k < 8) ? 9 * k : 8 * k + 8;
  const int c = (k < 8) ? 9 : 8;
  const int B = 8 * (u + 1);  // strip u's ct count; cts >= B belong to strip 63-u

  // segments: [0]=strip u part, [1]=strip 63-u part (at most one block straddles)
  const int aEnd = min(s + c, B);
  const int aCnt = max(0, aEnd - s);
  const int bStart = max(s, B);
  const int bCnt = max(0, s + c - bStart);
  int segR0[2], segCol[2], segCnt[2], segLds[2];
  segR0[0] = 128 * u;        segCol[0] = s * 16;              segCnt[0] = aCnt; segLds[0] = 0;
  segR0[1] = 128 * (63 - u); segCol[1] = (bStart - B) * 16;   segCnt[1] = bCnt; segLds[1] = aCnt;

  // zero this wave's col-credit region (wave-private, no sync needed)
  for (int i = lane; i < 144; i += 64) {
    colT_l[w * 144 + i] = 0.f;
    colG_l[w * 144 + i] = 0.f;
  }

  const f32x2 MK2 = {MKc, MKc}, PK2 = {PKc, PKc}, C1K2 = {C1Kc, C1Kc};
  const f32x2 KE2 = {KEc, KEc}, ZERO2 = {0.f, 0.f}, EPS2 = {1e-30f, 1e-30f};
  const f32x2 ONE2 = {1.f, 1.f};

  for (int seg = 0; seg < 2; seg++) {
    const int cnt = segCnt[seg];
    if (cnt == 0) continue;
    const int R0 = segR0[seg];
    const int colBase = segCol[seg];
    const int ldsBase = segLds[seg];

    // A fragments + row labels (wave w owns rows R0 + w*32 .. +31, 2 strips of 16)
    bf16x8 af[2][4];
    int plr[2][4], slr[2][4];
    for (int strip = 0; strip < 2; strip++) {
      const short* fa = (const short*)fbg + (size_t)(R0 + w * 32 + strip * 16 + lrow) * DD;
      for (int kk = 0; kk < 4; kk++)
        af[strip][kk] = __builtin_bit_cast(bf16x8, *(const short8*)(fa + kk * 32 + quad * 8));
      for (int r = 0; r < 4; r++) {
        int rowg = R0 + w * 32 + strip * 16 + quad * 4 + r;
        plr[strip][r] = plab[rowg];
        slr[strip][r] = slab[rowg];
      }
    }

    f32x2 t2[2][2], g2[2][2];
    for (int s_ = 0; s_ < 2; s_++)
      for (int p = 0; p < 2; p++) { t2[s_][p] = ZERO2; g2[s_][p] = ZERO2; }

    const short* bp = (const short*)fbg + (size_t)(colBase + lrow) * DD + quad * 8;
    int colg = colBase + lrow;

    for (int ct = 0; ct < cnt; ct++) {
      bf16x8 bf[4];
      for (int kk = 0; kk < 4; kk++)
        bf[kk] = __builtin_bit_cast(bf16x8, *(const short8*)(bp + kk * 32));
      bp += 16 * DD;

      f32x4 acc[2];
      for (int strip = 0; strip < 2; strip++) {
        f32x4 a0 = {0.f, 0.f, 0.f, 0.f};
        for (int kk = 0; kk < 4; kk++)
          a0 = __builtin_amdgcn_mfma_f32_16x16x32_bf16(af[strip][kk], bf[kk], a0, 0, 0, 0);
        acc[strip] = a0;
      }

      const int pc = plab[colg];
      const int sc = slab[colg];
      const bool mct = (colg - lrow + 240 >= R0);  // conservative: ct's cols can reach rows
      f32x2 colE = ZERO2, colL = ZERO2;

      for (int strip = 0; strip < 2; strip++) {
        for (int p = 0; p < 2; p++) {
          f32x2 s2 = {acc[strip][2 * p], acc[strip][2 * p + 1]};
          f32x2 tK = __builtin_elementwise_fma(s2, MK2, PK2);
          tK = __builtin_elementwise_max(tK, ZERO2);
          f32x2 dk = __builtin_elementwise_fma(s2, MK2, C1K2);
          f32x2 m = __builtin_elementwise_max(tK * dk, EPS2);
          f32x2 rq = {__builtin_amdgcn_rsqf(m.x), __builtin_amdgcn_rsqf(m.y)};
          f32x2 nd = tK * rq;
          f32x2 p1 = nd + ONE2;
          f32x2 rr = p1 * p1 * dk;
          f32x2 lg = {__log2f(rr.x), __log2f(rr.y)};
          f32x2 el = KE2 * lg;
          f32x2 e = {exp2f(el.x), exp2f(el.y)};
          const int r0 = 2 * p, r1 = 2 * p + 1;
          bool same0 = (pc == plr[strip][r0]) || (sc == slr[strip][r0]);
          bool same1 = (pc == plr[strip][r1]) || (sc == slr[strip][r1]);
          f32x2 em, lm;
          if (mct) {
            int rg0 = R0 + w * 32 + strip * 16 + quad * 4 + r0;
            bool ok0 = (colg < rg0);
            bool ok1 = (colg < rg0 + 1);
            em.x = ok0 ? e.x : 0.f;
            em.y = ok1 ? e.y : 0.f;
            lm.x = (same0 && ok0) ? lg.x : 0.f;
            lm.y = (same1 && ok1) ? lg.y : 0.f;
          } else {
            em = e;
            lm.x = same0 ? lg.x : 0.f;
            lm.y = same1 ? lg.y : 0.f;
          }
          t2[strip][p] += em;
          g2[strip][p] += lm;
          colE += em;
          colL += lm;
        }
      }

      // col credit: reduce across the 4 quads, accumulate in this wave's LDS region
      float cE = colE.x + colE.y;
      float cL = colL.x + colL.y;
      cE += __shfl_xor(cE, 16, 64);
      cE += __shfl_xor(cE, 32, 64);
      cL += __shfl_xor(cL, 16, 64);
      cL += __shfl_xor(cL, 32, 64);
      if (quad == 0) {
        colT_l[w * 144 + (ldsBase + ct) * 16 + lrow] += cE;
        colG_l[w * 144 + (ldsBase + ct) * 16 + lrow] += cL;
      }
      colg += 16;
    }

    // row-side flush for this segment: 16-lane reduce, per-row atomics
    for (int strip = 0; strip < 2; strip++) {
      for (int r = 0; r < 4; r++) {
        float t = t2[strip][r >> 1][r & 1];
        float g = g2[strip][r >> 1][r & 1];
        for (int off = 1; off < 16; off <<= 1) {
          t += __shfl_xor(t, off, 16);
          g += __shfl_xor(g, off, 16);
        }
        if (lrow == 0) {
          int rowg = R0 + w * 32 + strip * 16 + quad * 4 + r;
          atomicAdd(&totg[rowg], t);
          atomicAdd(&tposg[rowg], g);
        }
      }
    }
  }

  // col-side flush: combine the 4 wave regions, one atomic per col per block
  __syncthreads();
  const int total = (aCnt + bCnt) * 16;
  for (int i = tid; i < total; i += 256) {
    const int ct = i >> 4;
    const int cin = i & 15;
    int col;
    if (ct < aCnt) col = segCol[0] + (ct - segLds[0]) * 16 + cin;
    else col = segCol[1] + (ct - segLds[1]) * 16 + cin;
    float sE = colT_l[i] + colT_l[144 + i] + colT_l[288 + i] + colT_l[432 + i];
    float sL = colG_l[i] + colG_l[144 + i] + colG_l[288 + i] + colG_l[432 + i];
    atomicAdd(&totg[col], sE);
    atomicAdd(&tposg[col], sL);
  }
}

// ---------------- finalize: one 1024-thread block ----------------
__global__ __launch_bounds__(1024) void finalize_k(const float* __restrict__ totg,
                                                   const float* __restrict__ tposg,
                                                   const int* __restrict__ plab,
                                                   const int* __restrict__ slab,
                                                   float* __restrict__ out) {
  __shared__ int hist[512];
  __shared__ int cntP[32], cntS[16];
  __shared__ float redP[16], redV[16];
  const int tid = threadIdx.x;
  if (tid < 512) hist[tid] = 0;
  __syncthreads();
  for (int i = tid; i < NN; i += 1024)
    atomicAdd(&hist[plab[i] * 16 + slab[i]], 1);
  __syncthreads();
  if (tid < 32) {
    int s = 0;
    for (int j = 0; j < 16; j++) s += hist[tid * 16 + j];
    cntP[tid] = s;
  } else if (tid >= 64 && tid < 80) {
    int s = 0;
    for (int j = 0; j < 32; j++) s += hist[j * 16 + (tid - 64)];
    cntS[tid - 64] = s;
  }
  __syncthreads();
  float accP = 0.f, accV = 0.f;
  for (int i = tid; i < NN; i += 1024) {
    int pl = plab[i], sl = slab[i];
    int np = cntP[pl] + cntS[sl] - hist[pl * 16 + sl] - 1;
    if (np > 0) {
      accP += (KLc * tposg[i]) / (float)np - __logf(totg[i] + 1e-8f);
      accV += 1.f;
    }
  }
  for (int off = 32; off; off >>= 1) {
    accP += __shfl_xor(accP, off, 64);
    accV += __shfl_xor(accV, off, 64);
  }
  int wv = tid >> 6;
  if ((tid & 63) == 0) { redP[wv] = accP; redV[wv] = accV; }
  __syncthreads();
  if (tid == 0) {
    float sp = 0.f, sv = 0.f;
    for (int j = 0; j < 16; j++) { sp += redP[j]; sv += redV[j]; }
    float loss = -(sp / fmaxf(sv, 1.0f)) * 0.5f;  // * TEMPERATURE
    if (sv <= 0.0f || !__builtin_isfinite(loss)) loss = 0.0f;
    out[0] = loss;
  }
}

extern "C" void kernel_launch(void* const* d_in, const int* in_sizes, int n_in,
                              void* d_out, int out_size, void* d_ws, size_t ws_size,
                              hipStream_t stream) {
  const float* x = (const float*)d_in[0];
  const int* pl = (const int*)d_in[1];
  const int* sl = (const int*)d_in[2];
  char* ws = (char*)d_ws;
  __hip_bfloat16* fb = (__hip_bfloat16*)ws;    // 2,097,152 B
  float* totg = (float*)(ws + 2097152);        // 32 KB
  float* tposg = (float*)(ws + 2129920);       // 32 KB

  prep_kernel<<<NN / 16, 256, 0, stream>>>(x, fb, totg, tposg);
  fused_kernel<<<2048, 256, 0, stream>>>(fb, pl, sl, totg, tposg);
  finalize_k<<<1, 1024, 0, stream>>>(totg, tposg, pl, sl, (float*)d_out);
}

// Round 22
// 111.820 us; speedup vs baseline: 1.1234x; 1.1234x over previous
//
#include <hip/hip_runtime.h>
#include <hip/hip_bf16.h>

#define NN 8192
#define DD 128

typedef short short8 __attribute__((ext_vector_type(8)));
typedef __bf16 bf16x8 __attribute__((ext_vector_type(8)));
typedef float f32x4 __attribute__((ext_vector_type(4)));
typedef float f32x2 __attribute__((ext_vector_type(2)));

// unit-norm simplification (x2=y2=1):
//   d = 1 + c^2 - 2cs ;  q = nd^2 = 2c(1-s)/d ;  1-q = (1-c)^2/d exactly
//   rr = (1+nd)/(1-nd) = (1+nd)^2 * d/(1-c)^2
//   adc = -dist/T = KL*log2(rr) ; e = exp(adc) = exp2(KE*log2(rr))
// Symmetric: each unordered pair {i,j}, j<i computed once, credited to row i
// (registers) and col j (per-wave LDS). Complementary-strip pairing: strip I
// (128 rows) + strip 63-I = 520 cts constant; 32 slots/unit of 16-17 cts
// (8x17+24x16=520) -> 1024 blocks = 4 blocks/CU. SESSION-BEST CONFIG (R19:
// 113.6us total). Plateau notes: issue-25% / trans-33% / residencyx2 / manual
// ILP+prefetch all neutral-or-worse; HW caps ~4 blocks/CU (R21); fused is
// dependency-latency-bound at ~51us -- structural floor for this design.
#define MKc (-0.110803324099723f)   // -2c/(1-c)^2
#define PKc (0.110803324099723f)    // +2c/(1-c)^2
#define C1Kc (1.110803324099723f)   // (1+c^2)/(1-c)^2
#define KEc (-8.944271909999159f)   // -1/(sqrt_c*T)
#define KLc (-6.199696797323639f)   // KE*ln2

// ---------------- prep: normalize 16 rows/block -> bf16; zero accumulators ----------------
__global__ __launch_bounds__(256) void prep_kernel(const float* __restrict__ x,
                                                   __hip_bfloat16* __restrict__ fb,
                                                   float* __restrict__ totg,
                                                   float* __restrict__ tposg) {
  int r = threadIdx.x >> 4, sub = threadIdx.x & 15;
  int row = blockIdx.x * 16 + r;
  const float4 a = *(const float4*)(x + (size_t)row * DD + sub * 8);
  const float4 b = *(const float4*)(x + (size_t)row * DD + sub * 8 + 4);
  float ss = a.x * a.x + a.y * a.y + a.z * a.z + a.w * a.w +
             b.x * b.x + b.y * b.y + b.z * b.z + b.w * b.w;
  for (int off = 1; off < 16; off <<= 1) ss += __shfl_xor(ss, off, 16);
  float inv = 1.0f / fmaxf(sqrtf(ss), 1e-12f);
  float va[8] = {a.x, a.y, a.z, a.w, b.x, b.y, b.z, b.w};
  short8 h;
  for (int j = 0; j < 8; j++) {
    __hip_bfloat16 t = __float2bfloat16(va[j] * inv);
    h[j] = __builtin_bit_cast(short, t);
  }
  *(short8*)((short*)fb + (size_t)row * DD + sub * 8) = h;
  if (threadIdx.x < 16) {
    totg[blockIdx.x * 16 + threadIdx.x] = 0.f;
    tposg[blockIdx.x * 16 + threadIdx.x] = 0.f;
  }
}

// ---------------- fused symmetric, pair-balanced: 1024 blocks x 16-17 cts ----------------
// launch_bounds(256,2): natural VGPR, no spill (NEVER (256,4): 64-VGPR cap ->
// ~1GB scratch spill, R8/R9). No last-block finalize (R17: fences + 1-CU tail
// doubled fused time). Inner math identical to R16 (best validated, absmax 0.0).
__global__ __launch_bounds__(256, 2) void fused_kernel(
    const __hip_bfloat16* __restrict__ fbg,
    const int* __restrict__ plab, const int* __restrict__ slab,
    float* __restrict__ totg, float* __restrict__ tposg) {
  __shared__ float colT_l[4 * 272];    // per-wave col e-sums   (4352 B)
  __shared__ float colG_l[4 * 272];    // per-wave col lg-sums  (4352 B)

  const int tid = threadIdx.x;
  const int w = tid >> 6;
  const int lane = tid & 63;
  const int lrow = lane & 15;
  const int quad = lane >> 4;

  // block -> (unit u, slot k) -> ct window [s, s+c) over the unit's 520 cts
  const int u = blockIdx.x >> 5;
  const int k = blockIdx.x & 31;
  const int s = (k < 8) ? 17 * k : 16 * k + 8;
  const int c = (k < 8) ? 17 : 16;
  const int B = 8 * (u + 1);  // strip u's ct count; cts >= B belong to strip 63-u

  // segments: [0]=strip u part, [1]=strip 63-u part (at most one block straddles)
  const int aEnd = min(s + c, B);
  const int aCnt = max(0, aEnd - s);
  const int bStart = max(s, B);
  const int bCnt = max(0, s + c - bStart);
  int segR0[2], segCol[2], segCnt[2], segLds[2];
  segR0[0] = 128 * u;        segCol[0] = s * 16;              segCnt[0] = aCnt; segLds[0] = 0;
  segR0[1] = 128 * (63 - u); segCol[1] = (bStart - B) * 16;   segCnt[1] = bCnt; segLds[1] = aCnt;

  // zero this wave's col-credit region (wave-private, no sync needed)
  for (int i = lane; i < 272; i += 64) {
    colT_l[w * 272 + i] = 0.f;
    colG_l[w * 272 + i] = 0.f;
  }

  const f32x2 MK2 = {MKc, MKc}, PK2 = {PKc, PKc}, C1K2 = {C1Kc, C1Kc};
  const f32x2 KE2 = {KEc, KEc}, ZERO2 = {0.f, 0.f}, EPS2 = {1e-30f, 1e-30f};
  const f32x2 ONE2 = {1.f, 1.f};

  for (int seg = 0; seg < 2; seg++) {
    const int cnt = segCnt[seg];
    if (cnt == 0) continue;
    const int R0 = segR0[seg];
    const int colBase = segCol[seg];
    const int ldsBase = segLds[seg];

    // A fragments + row labels (wave w owns rows R0 + w*32 .. +31, 2 strips of 16)
    bf16x8 af[2][4];
    int plr[2][4], slr[2][4];
    for (int strip = 0; strip < 2; strip++) {
      const short* fa = (const short*)fbg + (size_t)(R0 + w * 32 + strip * 16 + lrow) * DD;
      for (int kk = 0; kk < 4; kk++)
        af[strip][kk] = __builtin_bit_cast(bf16x8, *(const short8*)(fa + kk * 32 + quad * 8));
      for (int r = 0; r < 4; r++) {
        int rowg = R0 + w * 32 + strip * 16 + quad * 4 + r;
        plr[strip][r] = plab[rowg];
        slr[strip][r] = slab[rowg];
      }
    }

    f32x2 t2[2][2], g2[2][2];
    for (int s_ = 0; s_ < 2; s_++)
      for (int p = 0; p < 2; p++) { t2[s_][p] = ZERO2; g2[s_][p] = ZERO2; }

    const short* bp = (const short*)fbg + (size_t)(colBase + lrow) * DD + quad * 8;
    int colg = colBase + lrow;

    for (int ct = 0; ct < cnt; ct++) {
      bf16x8 bf[4];
      for (int kk = 0; kk < 4; kk++)
        bf[kk] = __builtin_bit_cast(bf16x8, *(const short8*)(bp + kk * 32));
      bp += 16 * DD;

      f32x4 acc[2];
      for (int strip = 0; strip < 2; strip++) {
        f32x4 a0 = {0.f, 0.f, 0.f, 0.f};
        for (int kk = 0; kk < 4; kk++)
          a0 = __builtin_amdgcn_mfma_f32_16x16x32_bf16(af[strip][kk], bf[kk], a0, 0, 0, 0);
        acc[strip] = a0;
      }

      const int pc = plab[colg];
      const int sc = slab[colg];
      const bool mct = (colg - lrow + 240 >= R0);  // conservative: ct's cols can reach rows
      f32x2 colE = ZERO2, colL = ZERO2;

      for (int strip = 0; strip < 2; strip++) {
        for (int p = 0; p < 2; p++) {
          f32x2 s2 = {acc[strip][2 * p], acc[strip][2 * p + 1]};
          f32x2 tK = __builtin_elementwise_fma(s2, MK2, PK2);
          tK = __builtin_elementwise_max(tK, ZERO2);
          f32x2 dk = __builtin_elementwise_fma(s2, MK2, C1K2);
          f32x2 m = __builtin_elementwise_max(tK * dk, EPS2);
          f32x2 rq = {__builtin_amdgcn_rsqf(m.x), __builtin_amdgcn_rsqf(m.y)};
          f32x2 nd = tK * rq;
          f32x2 p1 = nd + ONE2;
          f32x2 rr = p1 * p1 * dk;
          f32x2 lg = {__log2f(rr.x), __log2f(rr.y)};
          f32x2 el = KE2 * lg;
          f32x2 e = {exp2f(el.x), exp2f(el.y)};
          const int r0 = 2 * p, r1 = 2 * p + 1;
          bool same0 = (pc == plr[strip][r0]) || (sc == slr[strip][r0]);
          bool same1 = (pc == plr[strip][r1]) || (sc == slr[strip][r1]);
          f32x2 em, lm;
          if (mct) {
            int rg0 = R0 + w * 32 + strip * 16 + quad * 4 + r0;
            bool ok0 = (colg < rg0);
            bool ok1 = (colg < rg0 + 1);
            em.x = ok0 ? e.x : 0.f;
            em.y = ok1 ? e.y : 0.f;
            lm.x = (same0 && ok0) ? lg.x : 0.f;
            lm.y = (same1 && ok1) ? lg.y : 0.f;
          } else {
            em = e;
            lm.x = same0 ? lg.x : 0.f;
            lm.y = same1 ? lg.y : 0.f;
          }
          t2[strip][p] += em;
          g2[strip][p] += lm;
          colE += em;
          colL += lm;
        }
      }

      // col credit: reduce across the 4 quads, accumulate in this wave's LDS region
      float cE = colE.x + colE.y;
      float cL = colL.x + colL.y;
      cE += __shfl_xor(cE, 16, 64);
      cE += __shfl_xor(cE, 32, 64);
      cL += __shfl_xor(cL, 16, 64);
      cL += __shfl_xor(cL, 32, 64);
      if (quad == 0) {
        colT_l[w * 272 + (ldsBase + ct) * 16 + lrow] += cE;
        colG_l[w * 272 + (ldsBase + ct) * 16 + lrow] += cL;
      }
      colg += 16;
    }

    // row-side flush for this segment: 16-lane reduce, per-row atomics
    for (int strip = 0; strip < 2; strip++) {
      for (int r = 0; r < 4; r++) {
        float t = t2[strip][r >> 1][r & 1];
        float g = g2[strip][r >> 1][r & 1];
        for (int off = 1; off < 16; off <<= 1) {
          t += __shfl_xor(t, off, 16);
          g += __shfl_xor(g, off, 16);
        }
        if (lrow == 0) {
          int rowg = R0 + w * 32 + strip * 16 + quad * 4 + r;
          atomicAdd(&totg[rowg], t);
          atomicAdd(&tposg[rowg], g);
        }
      }
    }
  }

  // col-side flush: combine the 4 wave regions, one atomic per col per block
  __syncthreads();
  const int total = (aCnt + bCnt) * 16;
  for (int i = tid; i < total; i += 256) {
    const int ct = i >> 4;
    const int cin = i & 15;
    int col;
    if (ct < aCnt) col = segCol[0] + (ct - segLds[0]) * 16 + cin;
    else col = segCol[1] + (ct - segLds[1]) * 16 + cin;
    float sE = colT_l[i] + colT_l[272 + i] + colT_l[544 + i] + colT_l[816 + i];
    float sL = colG_l[i] + colG_l[272 + i] + colG_l[544 + i] + colG_l[816 + i];
    atomicAdd(&totg[col], sE);
    atomicAdd(&tposg[col], sL);
  }
}

// ---------------- finalize: one 1024-thread block ----------------
__global__ __launch_bounds__(1024) void finalize_k(const float* __restrict__ totg,
                                                   const float* __restrict__ tposg,
                                                   const int* __restrict__ plab,
                                                   const int* __restrict__ slab,
                                                   float* __restrict__ out) {
  __shared__ int hist[512];
  __shared__ int cntP[32], cntS[16];
  __shared__ float redP[16], redV[16];
  const int tid = threadIdx.x;
  if (tid < 512) hist[tid] = 0;
  __syncthreads();
  for (int i = tid; i < NN; i += 1024)
    atomicAdd(&hist[plab[i] * 16 + slab[i]], 1);
  __syncthreads();
  if (tid < 32) {
    int s = 0;
    for (int j = 0; j < 16; j++) s += hist[tid * 16 + j];
    cntP[tid] = s;
  } else if (tid >= 64 && tid < 80) {
    int s = 0;
    for (int j = 0; j < 32; j++) s += hist[j * 16 + (tid - 64)];
    cntS[tid - 64] = s;
  }
  __syncthreads();
  float accP = 0.f, accV = 0.f;
  for (int i = tid; i < NN; i += 1024) {
    int pl = plab[i], sl = slab[i];
    int np = cntP[pl] + cntS[sl] - hist[pl * 16 + sl] - 1;
    if (np > 0) {
      accP += (KLc * tposg[i]) / (float)np - __logf(totg[i] + 1e-8f);
      accV += 1.f;
    }
  }
  for (int off = 32; off; off >>= 1) {
    accP += __shfl_xor(accP, off, 64);
    accV += __shfl_xor(accV, off, 64);
  }
  int wv = tid >> 6;
  if ((tid & 63) == 0) { redP[wv] = accP; redV[wv] = accV; }
  __syncthreads();
  if (tid == 0) {
    float sp = 0.f, sv = 0.f;
    for (int j = 0; j < 16; j++) { sp += redP[j]; sv += redV[j]; }
    float loss = -(sp / fmaxf(sv, 1.0f)) * 0.5f;  // * TEMPERATURE
    if (sv <= 0.0f || !__builtin_isfinite(loss)) loss = 0.0f;
    out[0] = loss;
  }
}

extern "C" void kernel_launch(void* const* d_in, const int* in_sizes, int n_in,
                              void* d_out, int out_size, void* d_ws, size_t ws_size,
                              hipStream_t stream) {
  const float* x = (const float*)d_in[0];
  const int* pl = (const int*)d_in[1];
  const int* sl = (const int*)d_in[2];
  char* ws = (char*)d_ws;
  __hip_bfloat16* fb = (__hip_bfloat16*)ws;    // 2,097,152 B
  float* totg = (float*)(ws + 2097152);        // 32 KB
  float* tposg = (float*)(ws + 2129920);       // 32 KB

  prep_kernel<<<NN / 16, 256, 0, stream>>>(x, fb, totg, tposg);
  fused_kernel<<<1024, 256, 0, stream>>>(fb, pl, sl, totg, tposg);
  finalize_k<<<1, 1024, 0, stream>>>(totg, tposg, pl, sl, (float*)d_out);
}